// Round 17
// baseline (33.551 us; speedup 1.0000x reference)
//
#include <hip/hip_runtime.h>

// Problem constants (from reference)
#define NQ 6
#define NF 4
#define GG 14
#define GG2 196
#define GG3 2744
#define NSIDE 12
#define PP 1728          // NSIDE^3
#define NC 40
#define BB 16
#define LAM 0.1f
#define FEAT_LEN (NF*PP*NQ)   // 41472
#define KCH 512
#define NCHUNK 81             // 41472 / 512
#define CTILES 5              // 40 / 8
#define NWAVE_IP2 (PP*4)      // 6912 = 128*54

typedef _Float16 h2 __attribute__((ext_vector_type(2)));

template<int CTRL>
__device__ __forceinline__ float fdpp(float v) {
    return __int_as_float(__builtin_amdgcn_mov_dpp(__float_as_int(v), CTRL, 0xF, 0xF, true));
}
#define DPP1(v) fdpp<0xB1>(v)    // quad_perm xor1 (VALU)
#define DPP2(v) fdpp<0x4E>(v)    // quad_perm xor2 (VALU)

__device__ __forceinline__ float asf(h2 v) { return __builtin_bit_cast(float, v); }
__device__ __forceinline__ h2 ash(float v) { return __builtin_bit_cast(h2, v); }
__device__ __forceinline__ h2 ashu(unsigned v) { return __builtin_bit_cast(h2, v); }
__device__ __forceinline__ h2 pk2(float a, float b) { return (h2){(_Float16)a, (_Float16)b}; }
__device__ __forceinline__ unsigned pku(float a, float b) {
    return __builtin_bit_cast(unsigned, pk2(a, b));
}
__device__ __forceinline__ unsigned pkh(float v) { return pku(v, v); }
__device__ __forceinline__ h2 dpp1h(h2 v) { return ash(DPP1(asf(v))); }
__device__ __forceinline__ h2 dpp2h(h2 v) { return ash(DPP2(asf(v))); }
__device__ __forceinline__ h2 shf4h(h2 v) { return ash(__shfl_xor(asf(v), 4)); }

// ---------- sim: 8 lanes per circuit-pair, 8 packed amps per lane ----------
// lane = [b5=c][b4b3=f][b2=q0][b1=q4][b0=q2] ; reg l = [bit2=q1][bit1=q3][bit0=q5]
// fp16 pack dim = circuit (b0 = w*2+c in .x, b1 = b0+8 in .y).
// Setup: stage A (168 thr x 3 sincos) -> stage B (48 thr compose+pack).
// block = 256 thr = 4 waves = one patch p; grid = PP.

__global__ __launch_bounds__(256) void sim_kernel(
    const float* __restrict__ x,      // [B,14,14,14]
    const float* __restrict__ theta,  // [NF,1,6,3]
    float* __restrict__ feats,        // [B][NF][PP][NQ]
    float* __restrict__ ip2)          // [NWAVE_IP2]
{
    const int t = threadIdx.x;
    const int w = t >> 6, lane = t & 63;
    const int c   = lane >> 5;
    const int f   = (lane >> 3) & 3;
    const int gq0 = (lane >> 2) & 1;
    const int gq4 = (lane >> 1) & 1;
    const int gq2 = lane & 1;
    const int p   = blockIdx.x;
    const int b0  = w*2 + c;          // 0..7 (= pair index)
    const int b1  = b0 + 8;           // 8..15

    __shared__ __align__(16) unsigned scroth[NF*NQ][8];   // packed h2 CRot coefs
    __shared__ __align__(16) float sA[BB][NQ][4];         // gate-q first columns
    __shared__ __align__(16) float sB[BB][3][8];          // gate-(q+6) full 2x2
    __shared__ __align__(16) unsigned scomph[8][NQ][4];   // packed composed cols

    const int px = p/(NSIDE*NSIDE), py = (p/NSIDE)%NSIDE, pz = p%NSIDE;
    #define SPV(i) xp[((i)/9)*GG2 + (((i)/3)%3)*GG + ((i)%3)]

    // ---- stage A: 168 threads, exactly 3 sincos each
    if (t < 96) {                     // first-column of gate q for (b2,q)
        const int b2 = t / 6, q = t % 6;
        const float* xp = x + (size_t)b2*GG3 + px*GG2 + py*GG + pz;
        float s, cc, sap, cap, sam, cam;
        __sincosf(0.5f*SPV(3*q+1), &s, &cc);
        __sincosf(0.5f*(SPV(3*q)+SPV(3*q+2)), &sap, &cap);
        __sincosf(0.5f*(SPV(3*q)-SPV(3*q+2)), &sam, &cam);
        sA[b2][q][0] = cap*cc; sA[b2][q][1] = -sap*cc;
        sA[b2][q][2] = cam*s;  sA[b2][q][3] = -sam*s;
    } else if (t < 144) {             // full 2x2 of gate qq+6 for (b2,qq)
        const int idx = t - 96, b2 = idx / 3, qq = idx % 3;
        const int k2 = 3*(qq+6);
        const float* xp = x + (size_t)b2*GG3 + px*GG2 + py*GG + pz;
        float s, cc, sap, cap, sam, cam;
        __sincosf(0.5f*SPV(k2+1), &s, &cc);
        __sincosf(0.5f*(SPV(k2)+SPV(k2+2)), &sap, &cap);
        __sincosf(0.5f*(SPV(k2)-SPV(k2+2)), &sam, &cam);
        sB[b2][qq][0] =  cap*cc; sB[b2][qq][1] = -sap*cc;   // b00
        sB[b2][qq][2] = -cam*s;  sB[b2][qq][3] = -sam*s;    // b01
        sB[b2][qq][4] =  cam*s;  sB[b2][qq][5] = -sam*s;    // b10
        sB[b2][qq][6] =  cap*cc; sB[b2][qq][7] =  sap*cc;   // b11
    } else if (t < 144 + NF*NQ) {     // CRot matrices (block-invariant), packed
        const int j = t - 144;
        const float* a = theta + j*3;
        float s, cc, sap, cap, sam, cam;
        __sincosf(0.5f*a[1], &s, &cc);
        __sincosf(0.5f*(a[0]+a[2]), &sap, &cap);
        __sincosf(0.5f*(a[0]-a[2]), &sam, &cam);
        scroth[j][0] = pkh( cap*cc); scroth[j][1] = pkh(-sap*cc);
        scroth[j][2] = pkh(-cam*s);  scroth[j][3] = pkh(-sam*s);
        scroth[j][4] = pkh( cam*s);  scroth[j][5] = pkh(-sam*s);
        scroth[j][6] = pkh( cap*cc); scroth[j][7] = pkh( sap*cc);
    }
    #undef SPV
    __syncthreads();

    // ---- stage B: 48 threads compose (q<3) and pack pairs (b2, b2+8)
    if (t < 48) {
        const int pr_ = t / 6, q = t % 6;
        float o[2][4];
        #pragma unroll
        for (int u = 0; u < 2; ++u) {
            const int b2 = pr_ + 8*u;
            float c0r = sA[b2][q][0], c0i = sA[b2][q][1];
            float c1r = sA[b2][q][2], c1i = sA[b2][q][3];
            if (q < 3) {
                const float* M = sB[b2][q];
                float n0r = M[0]*c0r - M[1]*c0i + M[2]*c1r - M[3]*c1i;
                float n0i = M[0]*c0i + M[1]*c0r + M[2]*c1i + M[3]*c1r;
                float n1r = M[4]*c0r - M[5]*c0i + M[6]*c1r - M[7]*c1i;
                float n1i = M[4]*c0i + M[5]*c0r + M[6]*c1i + M[7]*c1r;
                c0r=n0r; c0i=n0i; c1r=n1r; c1i=n1i;
            }
            o[u][0]=c0r; o[u][1]=c0i; o[u][2]=c1r; o[u][3]=c1i;
        }
        scomph[pr_][q][0] = pku(o[0][0], o[1][0]);
        scomph[pr_][q][1] = pku(o[0][1], o[1][1]);
        scomph[pr_][q][2] = pku(o[0][2], o[1][2]);
        scomph[pr_][q][3] = pku(o[0][3], o[1][3]);
    }
    __syncthreads();

    h2 hr[8], hi[8];

    // ---- encoding from packed columns (input |0>)
    {
        const uint4* scp = (const uint4*)&scomph[b0][0][0];   // 6 uint4
        uint4 C0 = scp[0], C1 = scp[1], C2 = scp[2];
        uint4 C3 = scp[3], C4 = scp[4], C5 = scp[5];
        h2 e0r = gq0 ? ashu(C0.z) : ashu(C0.x), e0i = gq0 ? ashu(C0.w) : ashu(C0.y);
        h2 e2r = gq2 ? ashu(C2.z) : ashu(C2.x), e2i = gq2 ? ashu(C2.w) : ashu(C2.y);
        h2 e4r = gq4 ? ashu(C4.z) : ashu(C4.x), e4i = gq4 ? ashu(C4.w) : ashu(C4.y);
        h2 t02r = e0r*e2r - e0i*e2i, t02i = e0r*e2i + e0i*e2r;
        h2 pfr = t02r*e4r - t02i*e4i, pfi = t02r*e4i + t02i*e4r;
        // q1 spread (reg bit2) from {0}
        {
            h2 c0r=ashu(C1.x), c0i=ashu(C1.y), c1r=ashu(C1.z), c1i=ashu(C1.w);
            hr[4] = c1r*pfr - c1i*pfi;  hi[4] = c1r*pfi + c1i*pfr;
            hr[0] = c0r*pfr - c0i*pfi;  hi[0] = c0r*pfi + c0i*pfr;
        }
        // q3 spread (reg bit1) on {0,4}
        {
            h2 c0r=ashu(C3.x), c0i=ashu(C3.y), c1r=ashu(C3.z), c1i=ashu(C3.w);
            #pragma unroll
            for (int l = 0; l <= 4; l += 4) {
                h2 r0 = hr[l], i0 = hi[l];
                hr[l+2] = c1r*r0 - c1i*i0;  hi[l+2] = c1r*i0 + c1i*r0;
                hr[l]   = c0r*r0 - c0i*i0;  hi[l]   = c0r*i0 + c0i*r0;
            }
        }
        // q5 spread (reg bit0) on {0,2,4,6}
        {
            h2 c0r=ashu(C5.x), c0i=ashu(C5.y), c1r=ashu(C5.z), c1i=ashu(C5.w);
            #pragma unroll
            for (int l = 0; l <= 6; l += 2) {
                h2 r0 = hr[l], i0 = hi[l];
                hr[l+1] = c1r*r0 - c1i*i0;  hi[l+1] = c1r*i0 + c1i*r0;
                hr[l]   = c0r*r0 - c0i*i0;  hi[l]   = c0r*i0 + c0i*r0;
            }
        }
    }

    const h2 H0 = (h2){(_Float16)0, (_Float16)0};
    const h2 H1 = (h2){(_Float16)1, (_Float16)1};
    const uint4* crp = (const uint4*)&scroth[f*NQ][0];

    // CR0: ctrl q0(lane b2), tgt q1(reg bit2): pairs (l,l+4); identity if !gq0
    {
        uint4 Au = crp[0], Bu = crp[1];
        h2 Ax=ashu(Au.x), Ay=ashu(Au.y), Az=ashu(Au.z), Aw=ashu(Au.w);
        h2 Bx=ashu(Bu.x), By=ashu(Bu.y), Bz=ashu(Bu.z), Bw=ashu(Bu.w);
        if (!gq0) { Ax=H1; Ay=H0; Az=H0; Aw=H0; Bx=H0; By=H0; Bz=H1; Bw=H0; }
        #pragma unroll
        for (int l = 0; l < 4; ++l) {
            const int l1 = l + 4;
            h2 a0r=hr[l], a0i=hi[l], a1r=hr[l1], a1i=hi[l1];
            hr[l]  = Ax*a0r - Ay*a0i + Az*a1r - Aw*a1i;
            hi[l]  = Ax*a0i + Ay*a0r + Az*a1i + Aw*a1r;
            hr[l1] = Bx*a0r - By*a0i + Bz*a1r - Bw*a1i;
            hi[l1] = Bx*a0i + By*a0r + Bz*a1i + Bw*a1r;
        }
    }
    // CR1: ctrl q1(reg bit2 -> l=4..7), tgt q2(lane b0) -> DPP xor1
    {
        uint4 Au = crp[2], Bu = crp[3];
        h2 Ax=ashu(Au.x), Ay=ashu(Au.y), Az=ashu(Au.z), Aw=ashu(Au.w);
        h2 Bx=ashu(Bu.x), By=ashu(Bu.y), Bz=ashu(Bu.z), Bw=ashu(Bu.w);
        h2 cAr = gq2 ? Bz : Ax, cAi = gq2 ? Bw : Ay;
        h2 cBr = gq2 ? Bx : Az, cBi = gq2 ? By : Aw;
        #pragma unroll
        for (int l = 4; l < 8; ++l) {
            h2 prr = dpp1h(hr[l]), pri = dpp1h(hi[l]);
            h2 nr = cAr*hr[l] - cAi*hi[l] + cBr*prr - cBi*pri;
            h2 ni = cAr*hi[l] + cAi*hr[l] + cBr*pri + cBi*prr;
            hr[l] = nr; hi[l] = ni;
        }
    }
    // CR2: ctrl q2(lane b0), tgt q3(reg bit1): pairs (l,l+2), identity if !gq2
    {
        uint4 Au = crp[4], Bu = crp[5];
        h2 Ax=ashu(Au.x), Ay=ashu(Au.y), Az=ashu(Au.z), Aw=ashu(Au.w);
        h2 Bx=ashu(Bu.x), By=ashu(Bu.y), Bz=ashu(Bu.z), Bw=ashu(Bu.w);
        if (!gq2) { Ax=H1; Ay=H0; Az=H0; Aw=H0; Bx=H0; By=H0; Bz=H1; Bw=H0; }
        #pragma unroll
        for (int li = 0; li < 4; ++li) {
            const int l = (li & 1) | ((li & 2) << 1);   // 0,1,4,5
            const int l1 = l + 2;
            h2 a0r=hr[l], a0i=hi[l], a1r=hr[l1], a1i=hi[l1];
            hr[l]  = Ax*a0r - Ay*a0i + Az*a1r - Aw*a1i;
            hi[l]  = Ax*a0i + Ay*a0r + Az*a1i + Aw*a1r;
            hr[l1] = Bx*a0r - By*a0i + Bz*a1r - Bw*a1i;
            hi[l1] = Bx*a0i + By*a0r + Bz*a1i + Bw*a1r;
        }
    }
    // CR3: ctrl q3(reg bit1 -> l in {2,3,6,7}), tgt q4(lane b1) -> DPP xor2
    {
        uint4 Au = crp[6], Bu = crp[7];
        h2 Ax=ashu(Au.x), Ay=ashu(Au.y), Az=ashu(Au.z), Aw=ashu(Au.w);
        h2 Bx=ashu(Bu.x), By=ashu(Bu.y), Bz=ashu(Bu.z), Bw=ashu(Bu.w);
        h2 cAr = gq4 ? Bz : Ax, cAi = gq4 ? Bw : Ay;
        h2 cBr = gq4 ? Bx : Az, cBi = gq4 ? By : Aw;
        #pragma unroll
        for (int li = 0; li < 4; ++li) {
            const int l = 2 + (li & 1) + ((li & 2) << 1);   // 2,3,6,7
            h2 prr = dpp2h(hr[l]), pri = dpp2h(hi[l]);
            h2 nr = cAr*hr[l] - cAi*hi[l] + cBr*prr - cBi*pri;
            h2 ni = cAr*hi[l] + cAi*hr[l] + cBr*pri + cBi*prr;
            hr[l] = nr; hi[l] = ni;
        }
    }
    // CR4: ctrl q4(lane b1), tgt q5(reg bit0): pairs (l,l+1), identity if !gq4
    {
        uint4 Au = crp[8], Bu = crp[9];
        h2 Ax=ashu(Au.x), Ay=ashu(Au.y), Az=ashu(Au.z), Aw=ashu(Au.w);
        h2 Bx=ashu(Bu.x), By=ashu(Bu.y), Bz=ashu(Bu.z), Bw=ashu(Bu.w);
        if (!gq4) { Ax=H1; Ay=H0; Az=H0; Aw=H0; Bx=H0; By=H0; Bz=H1; Bw=H0; }
        #pragma unroll
        for (int l = 0; l < 8; l += 2) {
            const int l1 = l + 1;
            h2 a0r=hr[l], a0i=hi[l], a1r=hr[l1], a1i=hi[l1];
            hr[l]  = Ax*a0r - Ay*a0i + Az*a1r - Aw*a1i;
            hi[l]  = Ax*a0i + Ay*a0r + Az*a1i + Aw*a1r;
            hr[l1] = Bx*a0r - By*a0i + Bz*a1r - Bw*a1i;
            hi[l1] = Bx*a0i + By*a0r + Bz*a1i + Bw*a1r;
        }
    }
    // CR5: ctrl q5(reg bit0 -> odd l), tgt q0(lane b2) -> shfl xor4
    {
        uint4 Au = crp[10], Bu = crp[11];
        h2 Ax=ashu(Au.x), Ay=ashu(Au.y), Az=ashu(Au.z), Aw=ashu(Au.w);
        h2 Bx=ashu(Bu.x), By=ashu(Bu.y), Bz=ashu(Bu.z), Bw=ashu(Bu.w);
        h2 cAr = gq0 ? Bz : Ax, cAi = gq0 ? Bw : Ay;
        h2 cBr = gq0 ? Bx : Az, cBi = gq0 ? By : Aw;
        #pragma unroll
        for (int l = 1; l < 8; l += 2) {
            h2 prr = shf4h(hr[l]), pri = shf4h(hi[l]);
            h2 nr = cAr*hr[l] - cAi*hi[l] + cBr*prr - cBi*pri;
            h2 ni = cAr*hi[l] + cAi*hr[l] + cBr*pri + cBi*prr;
            hr[l] = nr; hi[l] = ni;
        }
    }

    // ---- probabilities (packed; halves stay per-circuit)
    h2 ph[8];
    #pragma unroll
    for (int l = 0; l < 8; ++l) ph[l] = hr[l]*hr[l] + hi[l]*hi[l];

    // ---- loss pair-dots: f-partners at lane-xor 8,16,24; g-reduce DPP1/DPP2/shfl4
    float lc = 0.f;
    #pragma unroll
    for (int xi = 1; xi <= 3; ++xi) {
        const int xm = xi << 3;
        h2 d = H0;
        #pragma unroll
        for (int l = 0; l < 8; ++l) d += ph[l] * ash(__shfl_xor(asf(ph[l]), xm));
        d += dpp1h(d);
        d += dpp2h(d);
        d += shf4h(d);
        float d0 = (float)d.x, d1 = (float)d.y;
        lc += d0*d0 + d1*d1;
    }
    lc += DPP1(lc);
    lc += DPP2(lc);
    lc += __shfl_xor(lc, 4);
    lc += __shfl_xor(lc, 8);
    lc += __shfl_xor(lc, 16);
    lc += __shfl_xor(lc, 32);
    if (lane == 0) ip2[blockIdx.x*4 + w] = lc;   // 8x-counted; finalize /8

    // ---- expvals (packed): reg signed sums (q1,q3,q5), lane signs (q0,q2,q4)
    {
        h2 s04 = ph[0]+ph[4], s15 = ph[1]+ph[5], s26 = ph[2]+ph[6], s37 = ph[3]+ph[7];
        h2 eq1 = (ph[0]+ph[1]+ph[2]+ph[3]) - (ph[4]+ph[5]+ph[6]+ph[7]);
        h2 eq3 = (s04+s15) - (s26+s37);
        h2 eq5 = (s04+s26) - (s15+s37);
        h2 s   = (s04+s15) + (s26+s37);
        h2 eq0 = gq0 ? (H0 - s) : s;
        h2 eq2 = gq2 ? (H0 - s) : s;
        h2 eq4 = gq4 ? (H0 - s) : s;
        #define GRED(e) { e += dpp1h(e); e += dpp2h(e); e += shf4h(e); }
        GRED(eq0) GRED(eq1) GRED(eq2) GRED(eq3) GRED(eq4) GRED(eq5)
        #undef GRED
        if ((lane & 7) == 0) {        // one lane per (c,f)
            float* fo0 = feats + (((size_t)b0*NF + f)*PP + p)*NQ;
            float* fo1 = feats + (((size_t)b1*NF + f)*PP + p)*NQ;
            fo0[0]=(float)eq0.x; fo0[1]=(float)eq1.x; fo0[2]=(float)eq2.x;
            fo0[3]=(float)eq3.x; fo0[4]=(float)eq4.x; fo0[5]=(float)eq5.x;
            fo1[0]=(float)eq0.y; fo1[1]=(float)eq1.y; fo1[2]=(float)eq2.y;
            fo1[3]=(float)eq3.y; fo1[4]=(float)eq4.y; fo1[5]=(float)eq5.y;
        }
    }
}

// ---------- logits phase A: K-split, W read once ----------

__global__ __launch_bounds__(128) void logitsA(
    const float* __restrict__ feats,   // [BB][FEAT_LEN]
    const float* __restrict__ W,       // [NC][FEAT_LEN]
    float* __restrict__ partial)       // [NCHUNK][BB][NC]
{
    const int chunk = blockIdx.x;      // 0..80
    const int ctile = blockIdx.y;      // 0..4
    const int t = threadIdx.x;         // 128
    const int jbase = chunk * KCH;

    __shared__ __align__(16) float fs[BB][KCH + 4];

    #pragma unroll
    for (int i = 0; i < 16; ++i) {
        const int gi = i*128 + t;
        const int br = gi >> 7;
        const int c4 = gi & 127;
        float4 v = *(const float4*)(feats + (size_t)br*FEAT_LEN + jbase + c4*4);
        *(float4*)&fs[br][c4*4] = v;
    }
    __syncthreads();

    const int cl = t >> 4, b = t & 15;
    const int c = ctile*8 + cl;
    const float* wr = W + (size_t)c*FEAT_LEN + jbase;
    float acc = 0.f;
    #pragma unroll 8
    for (int j4 = 0; j4 < KCH/4; ++j4) {
        float4 wv = *(const float4*)(wr + j4*4);
        float4 fv = *(const float4*)&fs[b][j4*4];
        acc += wv.x*fv.x + wv.y*fv.y + wv.z*fv.z + wv.w*fv.w;
    }
    partial[((size_t)chunk*BB + b)*NC + c] = acc;
}

// ---------- phase B: logits reduce + bias (coalesced), loss reduce (unrolled) ----------

__global__ __launch_bounds__(768) void finalize_kernel(
    const float* __restrict__ partial, const float* __restrict__ bias,
    const float* __restrict__ ip2, float* __restrict__ out)
{
    const int t = threadIdx.x;
    __shared__ float red[2];

    if (t >= 640) {
        const int idx = t - 640;       // 128 threads, 54 strided loads each
        float acc = 0.f;
        #pragma unroll
        for (int k = 0; k < 54; ++k) acc += ip2[idx + k*128];
        #pragma unroll
        for (int m = 1; m < 64; m <<= 1) acc += __shfl_xor(acc, m);
        if ((idx & 63) == 0) red[idx >> 6] = acc;
    }
    __syncthreads();

    if (t < BB*NC) {
        const int b = t / NC, c = t % NC;   // consecutive t -> consecutive c
        float acc = bias[c];
        #pragma unroll
        for (int i = 0; i < NCHUNK; ++i)
            acc += partial[((size_t)i*BB + b)*NC + c];
        out[t] = acc;
    } else if (t == 640) {
        out[BB*NC] = (red[0] + red[1]) *
                     (LAM / (float)(NF*(NF-1)) / (float)BB * 0.125f);
    }
}

extern "C" void kernel_launch(void* const* d_in, const int* in_sizes, int n_in,
                              void* d_out, int out_size, void* d_ws, size_t ws_size,
                              hipStream_t stream) {
    const float* x     = (const float*)d_in[0];  // [16,14,14,14]
    const float* theta = (const float*)d_in[1];  // [4,1,6,3]
    const float* W     = (const float*)d_in[2];  // [40,41472]
    const float* bias  = (const float*)d_in[3];  // [40]
    float* out = (float*)d_out;                  // [640 logits][1 loss]

    float* feats   = (float*)d_ws;                       // BB*FEAT_LEN
    float* ip2     = feats + (size_t)BB * FEAT_LEN;      // NWAVE_IP2
    float* partial = ip2 + NWAVE_IP2;                    // NCHUNK*BB*NC

    sim_kernel<<<PP, 256, 0, stream>>>(x, theta, feats, ip2);
    logitsA<<<dim3(NCHUNK, CTILES), 128, 0, stream>>>(feats, W, partial);
    finalize_kernel<<<1, 768, 0, stream>>>(partial, bias, ip2, out);
}

// Round 18
// 30.370 us; speedup vs baseline: 1.1047x; 1.1047x over previous
//
#include <hip/hip_runtime.h>

// Problem constants (from reference)
#define NQ 6
#define NF 4
#define GG 14
#define GG2 196
#define GG3 2744
#define NSIDE 12
#define PP 1728          // NSIDE^3
#define NC 40
#define BB 16
#define LAM 0.1f
#define FEAT_LEN (NF*PP*NQ)   // 41472
#define KCH 512
#define NCHUNK 81             // 41472 / 512
#define CTILES 5              // 40 / 8
#define NWAVE_IP2 (PP*4)      // 6912 = 128*54

typedef _Float16 h2 __attribute__((ext_vector_type(2)));

template<int CTRL>
__device__ __forceinline__ float fdpp(float v) {
    return __int_as_float(__builtin_amdgcn_mov_dpp(__float_as_int(v), CTRL, 0xF, 0xF, true));
}
#define DPP1(v) fdpp<0xB1>(v)    // quad_perm xor1 (VALU)
#define DPP2(v) fdpp<0x4E>(v)    // quad_perm xor2 (VALU)

__device__ __forceinline__ float asf(h2 v) { return __builtin_bit_cast(float, v); }
__device__ __forceinline__ h2 ash(float v) { return __builtin_bit_cast(h2, v); }
__device__ __forceinline__ h2 ashu(unsigned v) { return __builtin_bit_cast(h2, v); }
__device__ __forceinline__ h2 pk2(float a, float b) { return (h2){(_Float16)a, (_Float16)b}; }
__device__ __forceinline__ unsigned pkh(float v) {
    _Float16 h = (_Float16)v; h2 p = {h, h};
    return __builtin_bit_cast(unsigned, p);
}
__device__ __forceinline__ h2 dpp1h(h2 v) { return ash(DPP1(asf(v))); }
__device__ __forceinline__ h2 dpp2h(h2 v) { return ash(DPP2(asf(v))); }
__device__ __forceinline__ h2 shf4h(h2 v) { return ash(__shfl_xor(asf(v), 4)); }

// ---------- sim: 8 lanes per circuit-pair, 8 packed amps per lane ----------
// lane = [b5=c][b4b3=f][b2=q0][b1=q4][b0=q2] ; reg l = [bit2=q1][bit1=q3][bit0=q5]
// fp16 pack dim = circuit (b0 = w*2+c in .x, b1 = b0+8 in .y). Gate coefficients
// are lane-uniform -> shared by both halves; cross-lane DPP/shfl move both.
// block = 256 thr = 4 waves = one patch p; grid = PP.

__global__ __launch_bounds__(256) void sim_kernel(
    const float* __restrict__ x,      // [B,14,14,14]
    const float* __restrict__ theta,  // [NF,1,6,3]
    float* __restrict__ feats,        // [B][NF][PP][NQ]
    float* __restrict__ ip2)          // [NWAVE_IP2]
{
    const int t = threadIdx.x;
    const int w = t >> 6, lane = t & 63;
    const int c   = lane >> 5;
    const int f   = (lane >> 3) & 3;
    const int gq0 = (lane >> 2) & 1;
    const int gq4 = (lane >> 1) & 1;
    const int gq2 = lane & 1;
    const int p   = blockIdx.x;
    const int b0  = w*2 + c;          // 0..7
    const int b1  = b0 + 8;           // 8..15

    __shared__ __align__(16) unsigned scroth[NF*NQ][8];   // packed h2 CRot coefs
    __shared__ __align__(16) float scomp[BB][NQ][4];      // composed enc columns

    const int px = p/(NSIDE*NSIDE), py = (p/NSIDE)%NSIDE, pz = p%NSIDE;

    // threads 96..119: CRot matrices (block-invariant), stored packed
    if (t >= 96 && t < 96 + NF*NQ) {
        const int j = t - 96;
        const float* a = theta + j*3;
        float s, cc, sap, cap, sam, cam;
        __sincosf(0.5f*a[1], &s, &cc);
        __sincosf(0.5f*(a[0]+a[2]), &sap, &cap);
        __sincosf(0.5f*(a[0]-a[2]), &sam, &cam);
        scroth[j][0] = pkh( cap*cc); scroth[j][1] = pkh(-sap*cc);
        scroth[j][2] = pkh(-cam*s);  scroth[j][3] = pkh(-sam*s);
        scroth[j][4] = pkh( cam*s);  scroth[j][5] = pkh(-sam*s);
        scroth[j][6] = pkh( cap*cc); scroth[j][7] = pkh( sap*cc);
    }
    // threads 0..95: composed encoding columns for all (b2, q)
    if (t < BB*NQ) {
        const int b2 = t / NQ, q = t % NQ;
        const float* xp = x + (size_t)b2*GG3 + px*GG2 + py*GG + pz;
        #define SPV(i) xp[((i)/9)*GG2 + (((i)/3)%3)*GG + ((i)%3)]
        float s, cc, sap, cap, sam, cam;
        __sincosf(0.5f*SPV(3*q+1), &s, &cc);
        __sincosf(0.5f*(SPV(3*q)+SPV(3*q+2)), &sap, &cap);
        __sincosf(0.5f*(SPV(3*q)-SPV(3*q+2)), &sam, &cam);
        float c0r = cap*cc, c0i = -sap*cc, c1r = cam*s, c1i = -sam*s;
        if (q < 3) {   // compose with gate q+6 (applied second)
            const int k2 = 3*(q+6);
            float s_,c_,sap_,cap_,sam_,cam_;
            __sincosf(0.5f*SPV(k2+1), &s_, &c_);
            __sincosf(0.5f*(SPV(k2)+SPV(k2+2)), &sap_, &cap_);
            __sincosf(0.5f*(SPV(k2)-SPV(k2+2)), &sam_, &cam_);
            float b00r=cap_*c_, b00i=-sap_*c_, b01r=-cam_*s_, b01i=-sam_*s_;
            float b10r=cam_*s_, b10i=-sam_*s_, b11r=cap_*c_,  b11i= sap_*c_;
            float n0r = b00r*c0r - b00i*c0i + b01r*c1r - b01i*c1i;
            float n0i = b00r*c0i + b00i*c0r + b01r*c1i + b01i*c1r;
            float n1r = b10r*c0r - b10i*c0i + b11r*c1r - b11i*c1i;
            float n1i = b10r*c0i + b10i*c0r + b11r*c1i + b11i*c1r;
            c0r=n0r; c0i=n0i; c1r=n1r; c1i=n1i;
        }
        #undef SPV
        scomp[b2][q][0]=c0r; scomp[b2][q][1]=c0i;
        scomp[b2][q][2]=c1r; scomp[b2][q][3]=c1i;
    }
    __syncthreads();

    h2 hr[8], hi[8];

    // ---- encoding: packed product state (both circuits at once)
    {
        float4 C0a = *(const float4*)&scomp[b0][0][0];
        float4 C0b = *(const float4*)&scomp[b1][0][0];
        float4 C2a = *(const float4*)&scomp[b0][2][0];
        float4 C2b = *(const float4*)&scomp[b1][2][0];
        float4 C4a = *(const float4*)&scomp[b0][4][0];
        float4 C4b = *(const float4*)&scomp[b1][4][0];
        h2 e0r = pk2(gq0 ? C0a.z : C0a.x, gq0 ? C0b.z : C0b.x);
        h2 e0i = pk2(gq0 ? C0a.w : C0a.y, gq0 ? C0b.w : C0b.y);
        h2 e2r = pk2(gq2 ? C2a.z : C2a.x, gq2 ? C2b.z : C2b.x);
        h2 e2i = pk2(gq2 ? C2a.w : C2a.y, gq2 ? C2b.w : C2b.y);
        h2 e4r = pk2(gq4 ? C4a.z : C4a.x, gq4 ? C4b.z : C4b.x);
        h2 e4i = pk2(gq4 ? C4a.w : C4a.y, gq4 ? C4b.w : C4b.y);
        h2 t02r = e0r*e2r - e0i*e2i, t02i = e0r*e2i + e0i*e2r;
        h2 pfr = t02r*e4r - t02i*e4i, pfi = t02r*e4i + t02i*e4r;
        float4 C1a = *(const float4*)&scomp[b0][1][0];
        float4 C1b = *(const float4*)&scomp[b1][1][0];
        float4 C3a = *(const float4*)&scomp[b0][3][0];
        float4 C3b = *(const float4*)&scomp[b1][3][0];
        float4 C5a = *(const float4*)&scomp[b0][5][0];
        float4 C5b = *(const float4*)&scomp[b1][5][0];
        // q1 spread (reg bit2) from {0}
        {
            h2 c0r=pk2(C1a.x,C1b.x), c0i=pk2(C1a.y,C1b.y);
            h2 c1r=pk2(C1a.z,C1b.z), c1i=pk2(C1a.w,C1b.w);
            hr[4] = c1r*pfr - c1i*pfi;  hi[4] = c1r*pfi + c1i*pfr;
            hr[0] = c0r*pfr - c0i*pfi;  hi[0] = c0r*pfi + c0i*pfr;
        }
        // q3 spread (reg bit1) on {0,4}
        {
            h2 c0r=pk2(C3a.x,C3b.x), c0i=pk2(C3a.y,C3b.y);
            h2 c1r=pk2(C3a.z,C3b.z), c1i=pk2(C3a.w,C3b.w);
            #pragma unroll
            for (int l = 0; l <= 4; l += 4) {
                h2 r0 = hr[l], i0 = hi[l];
                hr[l+2] = c1r*r0 - c1i*i0;  hi[l+2] = c1r*i0 + c1i*r0;
                hr[l]   = c0r*r0 - c0i*i0;  hi[l]   = c0r*i0 + c0i*r0;
            }
        }
        // q5 spread (reg bit0) on {0,2,4,6}
        {
            h2 c0r=pk2(C5a.x,C5b.x), c0i=pk2(C5a.y,C5b.y);
            h2 c1r=pk2(C5a.z,C5b.z), c1i=pk2(C5a.w,C5b.w);
            #pragma unroll
            for (int l = 0; l <= 6; l += 2) {
                h2 r0 = hr[l], i0 = hi[l];
                hr[l+1] = c1r*r0 - c1i*i0;  hi[l+1] = c1r*i0 + c1i*r0;
                hr[l]   = c0r*r0 - c0i*i0;  hi[l]   = c0r*i0 + c0i*r0;
            }
        }
    }

    const h2 H0 = (h2){(_Float16)0, (_Float16)0};
    const h2 H1 = (h2){(_Float16)1, (_Float16)1};
    const uint4* crp = (const uint4*)&scroth[f*NQ][0];

    // CR0: ctrl q0(lane b2), tgt q1(reg bit2): pairs (l,l+4); identity if !gq0
    {
        uint4 Au = crp[0], Bu = crp[1];
        h2 Ax=ashu(Au.x), Ay=ashu(Au.y), Az=ashu(Au.z), Aw=ashu(Au.w);
        h2 Bx=ashu(Bu.x), By=ashu(Bu.y), Bz=ashu(Bu.z), Bw=ashu(Bu.w);
        if (!gq0) { Ax=H1; Ay=H0; Az=H0; Aw=H0; Bx=H0; By=H0; Bz=H1; Bw=H0; }
        #pragma unroll
        for (int l = 0; l < 4; ++l) {
            const int l1 = l + 4;
            h2 a0r=hr[l], a0i=hi[l], a1r=hr[l1], a1i=hi[l1];
            hr[l]  = Ax*a0r - Ay*a0i + Az*a1r - Aw*a1i;
            hi[l]  = Ax*a0i + Ay*a0r + Az*a1i + Aw*a1r;
            hr[l1] = Bx*a0r - By*a0i + Bz*a1r - Bw*a1i;
            hi[l1] = Bx*a0i + By*a0r + Bz*a1i + Bw*a1r;
        }
    }
    // CR1: ctrl q1(reg bit2 -> l=4..7), tgt q2(lane b0) -> DPP xor1
    {
        uint4 Au = crp[2], Bu = crp[3];
        h2 Ax=ashu(Au.x), Ay=ashu(Au.y), Az=ashu(Au.z), Aw=ashu(Au.w);
        h2 Bx=ashu(Bu.x), By=ashu(Bu.y), Bz=ashu(Bu.z), Bw=ashu(Bu.w);
        h2 cAr = gq2 ? Bz : Ax, cAi = gq2 ? Bw : Ay;
        h2 cBr = gq2 ? Bx : Az, cBi = gq2 ? By : Aw;
        #pragma unroll
        for (int l = 4; l < 8; ++l) {
            h2 prr = dpp1h(hr[l]), pri = dpp1h(hi[l]);
            h2 nr = cAr*hr[l] - cAi*hi[l] + cBr*prr - cBi*pri;
            h2 ni = cAr*hi[l] + cAi*hr[l] + cBr*pri + cBi*prr;
            hr[l] = nr; hi[l] = ni;
        }
    }
    // CR2: ctrl q2(lane b0), tgt q3(reg bit1): pairs (l,l+2), identity if !gq2
    {
        uint4 Au = crp[4], Bu = crp[5];
        h2 Ax=ashu(Au.x), Ay=ashu(Au.y), Az=ashu(Au.z), Aw=ashu(Au.w);
        h2 Bx=ashu(Bu.x), By=ashu(Bu.y), Bz=ashu(Bu.z), Bw=ashu(Bu.w);
        if (!gq2) { Ax=H1; Ay=H0; Az=H0; Aw=H0; Bx=H0; By=H0; Bz=H1; Bw=H0; }
        #pragma unroll
        for (int li = 0; li < 4; ++li) {
            const int l = (li & 1) | ((li & 2) << 1);   // 0,1,4,5
            const int l1 = l + 2;
            h2 a0r=hr[l], a0i=hi[l], a1r=hr[l1], a1i=hi[l1];
            hr[l]  = Ax*a0r - Ay*a0i + Az*a1r - Aw*a1i;
            hi[l]  = Ax*a0i + Ay*a0r + Az*a1i + Aw*a1r;
            hr[l1] = Bx*a0r - By*a0i + Bz*a1r - Bw*a1i;
            hi[l1] = Bx*a0i + By*a0r + Bz*a1i + Bw*a1r;
        }
    }
    // CR3: ctrl q3(reg bit1 -> l in {2,3,6,7}), tgt q4(lane b1) -> DPP xor2
    {
        uint4 Au = crp[6], Bu = crp[7];
        h2 Ax=ashu(Au.x), Ay=ashu(Au.y), Az=ashu(Au.z), Aw=ashu(Au.w);
        h2 Bx=ashu(Bu.x), By=ashu(Bu.y), Bz=ashu(Bu.z), Bw=ashu(Bu.w);
        h2 cAr = gq4 ? Bz : Ax, cAi = gq4 ? Bw : Ay;
        h2 cBr = gq4 ? Bx : Az, cBi = gq4 ? By : Aw;
        #pragma unroll
        for (int li = 0; li < 4; ++li) {
            const int l = 2 + (li & 1) + ((li & 2) << 1);   // 2,3,6,7
            h2 prr = dpp2h(hr[l]), pri = dpp2h(hi[l]);
            h2 nr = cAr*hr[l] - cAi*hi[l] + cBr*prr - cBi*pri;
            h2 ni = cAr*hi[l] + cAi*hr[l] + cBr*pri + cBi*prr;
            hr[l] = nr; hi[l] = ni;
        }
    }
    // CR4: ctrl q4(lane b1), tgt q5(reg bit0): pairs (l,l+1), identity if !gq4
    {
        uint4 Au = crp[8], Bu = crp[9];
        h2 Ax=ashu(Au.x), Ay=ashu(Au.y), Az=ashu(Au.z), Aw=ashu(Au.w);
        h2 Bx=ashu(Bu.x), By=ashu(Bu.y), Bz=ashu(Bu.z), Bw=ashu(Bu.w);
        if (!gq4) { Ax=H1; Ay=H0; Az=H0; Aw=H0; Bx=H0; By=H0; Bz=H1; Bw=H0; }
        #pragma unroll
        for (int l = 0; l < 8; l += 2) {
            const int l1 = l + 1;
            h2 a0r=hr[l], a0i=hi[l], a1r=hr[l1], a1i=hi[l1];
            hr[l]  = Ax*a0r - Ay*a0i + Az*a1r - Aw*a1i;
            hi[l]  = Ax*a0i + Ay*a0r + Az*a1i + Aw*a1r;
            hr[l1] = Bx*a0r - By*a0i + Bz*a1r - Bw*a1i;
            hi[l1] = Bx*a0i + By*a0r + Bz*a1i + Bw*a1r;
        }
    }
    // CR5: ctrl q5(reg bit0 -> odd l), tgt q0(lane b2) -> shfl xor4
    {
        uint4 Au = crp[10], Bu = crp[11];
        h2 Ax=ashu(Au.x), Ay=ashu(Au.y), Az=ashu(Au.z), Aw=ashu(Au.w);
        h2 Bx=ashu(Bu.x), By=ashu(Bu.y), Bz=ashu(Bu.z), Bw=ashu(Bu.w);
        h2 cAr = gq0 ? Bz : Ax, cAi = gq0 ? Bw : Ay;
        h2 cBr = gq0 ? Bx : Az, cBi = gq0 ? By : Aw;
        #pragma unroll
        for (int l = 1; l < 8; l += 2) {
            h2 prr = shf4h(hr[l]), pri = shf4h(hi[l]);
            h2 nr = cAr*hr[l] - cAi*hi[l] + cBr*prr - cBi*pri;
            h2 ni = cAr*hi[l] + cAi*hr[l] + cBr*pri + cBi*prr;
            hr[l] = nr; hi[l] = ni;
        }
    }

    // ---- probabilities (packed; halves stay per-circuit)
    h2 ph[8];
    #pragma unroll
    for (int l = 0; l < 8; ++l) ph[l] = hr[l]*hr[l] + hi[l]*hi[l];

    // ---- loss pair-dots: f-partners at lane-xor 8,16,24; g-reduce DPP1/DPP2/shfl4
    float lc = 0.f;
    #pragma unroll
    for (int xi = 1; xi <= 3; ++xi) {
        const int xm = xi << 3;
        h2 d = H0;
        #pragma unroll
        for (int l = 0; l < 8; ++l) d += ph[l] * ash(__shfl_xor(asf(ph[l]), xm));
        d += dpp1h(d);
        d += dpp2h(d);
        d += shf4h(d);
        float d0 = (float)d.x, d1 = (float)d.y;
        lc += d0*d0 + d1*d1;
    }
    lc += DPP1(lc);
    lc += DPP2(lc);
    lc += __shfl_xor(lc, 4);
    lc += __shfl_xor(lc, 8);
    lc += __shfl_xor(lc, 16);
    lc += __shfl_xor(lc, 32);
    if (lane == 0) ip2[blockIdx.x*4 + w] = lc;   // 8x-counted; finalize /8

    // ---- expvals (packed): reg signed sums (q1,q3,q5), lane signs (q0,q2,q4)
    {
        h2 s04 = ph[0]+ph[4], s15 = ph[1]+ph[5], s26 = ph[2]+ph[6], s37 = ph[3]+ph[7];
        h2 eq1 = (ph[0]+ph[1]+ph[2]+ph[3]) - (ph[4]+ph[5]+ph[6]+ph[7]);
        h2 eq3 = (s04+s15) - (s26+s37);
        h2 eq5 = (s04+s26) - (s15+s37);
        h2 s   = (s04+s15) + (s26+s37);
        h2 eq0 = gq0 ? (H0 - s) : s;
        h2 eq2 = gq2 ? (H0 - s) : s;
        h2 eq4 = gq4 ? (H0 - s) : s;
        #define GRED(e) { e += dpp1h(e); e += dpp2h(e); e += shf4h(e); }
        GRED(eq0) GRED(eq1) GRED(eq2) GRED(eq3) GRED(eq4) GRED(eq5)
        #undef GRED
        if ((lane & 7) == 0) {        // one lane per (c,f)
            float* fo0 = feats + (((size_t)b0*NF + f)*PP + p)*NQ;
            float* fo1 = feats + (((size_t)b1*NF + f)*PP + p)*NQ;
            fo0[0]=(float)eq0.x; fo0[1]=(float)eq1.x; fo0[2]=(float)eq2.x;
            fo0[3]=(float)eq3.x; fo0[4]=(float)eq4.x; fo0[5]=(float)eq5.x;
            fo1[0]=(float)eq0.y; fo1[1]=(float)eq1.y; fo1[2]=(float)eq2.y;
            fo1[3]=(float)eq3.y; fo1[4]=(float)eq4.y; fo1[5]=(float)eq5.y;
        }
    }
}

// ---------- logits phase A: K-split, W read once ----------

__global__ __launch_bounds__(128) void logitsA(
    const float* __restrict__ feats,   // [BB][FEAT_LEN]
    const float* __restrict__ W,       // [NC][FEAT_LEN]
    float* __restrict__ partial)       // [NCHUNK][BB][NC]
{
    const int chunk = blockIdx.x;      // 0..80
    const int ctile = blockIdx.y;      // 0..4
    const int t = threadIdx.x;         // 128
    const int jbase = chunk * KCH;

    __shared__ __align__(16) float fs[BB][KCH + 4];

    #pragma unroll
    for (int i = 0; i < 16; ++i) {
        const int gi = i*128 + t;
        const int br = gi >> 7;
        const int c4 = gi & 127;
        float4 v = *(const float4*)(feats + (size_t)br*FEAT_LEN + jbase + c4*4);
        *(float4*)&fs[br][c4*4] = v;
    }
    __syncthreads();

    const int cl = t >> 4, b = t & 15;
    const int c = ctile*8 + cl;
    const float* wr = W + (size_t)c*FEAT_LEN + jbase;
    float acc = 0.f;
    #pragma unroll 8
    for (int j4 = 0; j4 < KCH/4; ++j4) {
        float4 wv = *(const float4*)(wr + j4*4);
        float4 fv = *(const float4*)&fs[b][j4*4];
        acc += wv.x*fv.x + wv.y*fv.y + wv.z*fv.z + wv.w*fv.w;
    }
    partial[((size_t)chunk*BB + b)*NC + c] = acc;
}

// ---------- phase B: logits reduce + bias (coalesced), loss reduce (unrolled) ----------

__global__ __launch_bounds__(768) void finalize_kernel(
    const float* __restrict__ partial, const float* __restrict__ bias,
    const float* __restrict__ ip2, float* __restrict__ out)
{
    const int t = threadIdx.x;
    __shared__ float red[2];

    if (t >= 640) {
        const int idx = t - 640;       // 128 threads, 54 strided loads each
        float acc = 0.f;
        #pragma unroll
        for (int k = 0; k < 54; ++k) acc += ip2[idx + k*128];
        #pragma unroll
        for (int m = 1; m < 64; m <<= 1) acc += __shfl_xor(acc, m);
        if ((idx & 63) == 0) red[idx >> 6] = acc;
    }
    __syncthreads();

    if (t < BB*NC) {
        const int b = t / NC, c = t % NC;   // consecutive t -> consecutive c
        float acc = bias[c];
        #pragma unroll
        for (int i = 0; i < NCHUNK; ++i)
            acc += partial[((size_t)i*BB + b)*NC + c];
        out[t] = acc;
    } else if (t == 640) {
        out[BB*NC] = (red[0] + red[1]) *
                     (LAM / (float)(NF*(NF-1)) / (float)BB * 0.125f);
    }
}

extern "C" void kernel_launch(void* const* d_in, const int* in_sizes, int n_in,
                              void* d_out, int out_size, void* d_ws, size_t ws_size,
                              hipStream_t stream) {
    const float* x     = (const float*)d_in[0];  // [16,14,14,14]
    const float* theta = (const float*)d_in[1];  // [4,1,6,3]
    const float* W     = (const float*)d_in[2];  // [40,41472]
    const float* bias  = (const float*)d_in[3];  // [40]
    float* out = (float*)d_out;                  // [640 logits][1 loss]

    float* feats   = (float*)d_ws;                       // BB*FEAT_LEN
    float* ip2     = feats + (size_t)BB * FEAT_LEN;      // NWAVE_IP2
    float* partial = ip2 + NWAVE_IP2;                    // NCHUNK*BB*NC

    sim_kernel<<<PP, 256, 0, stream>>>(x, theta, feats, ip2);
    logitsA<<<dim3(NCHUNK, CTILES), 128, 0, stream>>>(feats, W, partial);
    finalize_kernel<<<1, 768, 0, stream>>>(partial, bias, ip2, out);
}